// Round 13
// baseline (112.787 us; speedup 1.0000x reference)
//
#include <hip/hip_runtime.h>

// Mo3ENet neighbor selection: B=256, PER=1024, NIN=256, NOUT=768, K=32, R=6
// Round 13: full-residency persistent tiles. 2048 blocks (8/CU, all resident:
// 16 KB LDS x 8 = 128 KB, 32 waves/CU), each stages its batch once and loops
// over 4 target-sets (32 targets/block). Inner machinery = r12 (ballot
// compaction -> LDS slot rows -> coalesced epilogue, single-group pads,
// biased io counter); scan loads via pair-SoA ds_read_b64 (r10 layout).
// Outputs (concatenated float32):
//   [0) src_ii | [E) tgt | [2E) m_ii | [3E) dist_ii |
//   [4E) src_io | [5E) tgt | [6E) m_io | [7E) dist_io
//
// Per-wave, per-target LDS slot row (128 ints): [0..31] ii | [32..63] io |
// [64..127] dead (dump). Conditional writes select dump unless (mine && in
// range), so overflow never clobbers live slots.

constexpr int KK = 32;
constexpr unsigned EE = 2097152u;  // elements per output array

typedef float v2f __attribute__((ext_vector_type(2)));

__device__ __forceinline__ v2f pk_add(v2f a, v2f b) {
    v2f d; asm("v_pk_add_f32 %0, %1, %2" : "=v"(d) : "v"(a), "v"(b)); return d;
}
__device__ __forceinline__ v2f pk_mul(v2f a, v2f b) {
    v2f d; asm("v_pk_mul_f32 %0, %1, %2" : "=v"(d) : "v"(a), "v"(b)); return d;
}

__device__ __forceinline__ int prefix_base(unsigned long long m, int base) {
    return __builtin_amdgcn_mbcnt_hi((unsigned)(m >> 32),
           __builtin_amdgcn_mbcnt_lo((unsigned)m, (unsigned)base));
}

// pair-SoA float index of point j: v2f slot ((j>>7)*64 + (j&63)), half (j>>6)&1
__device__ __forceinline__ int fo_of(int j) {
    return ((((j >> 7) << 6) | (j & 63)) << 1) | ((j >> 6) & 1);
}

__global__ __launch_bounds__(256) void mo3e_kernel(const float* __restrict__ pos,
                                                   float* __restrict__ out) {
    __shared__ v2f sqx[512], sqy[512], sqz[512];  // 12 KB pair-SoA coords
    __shared__ int slotrow[4][2][128];            // 4 KB: per wave x per target

    const int blk = blockIdx.x;
    const int b   = blk >> 3;             // 8 blocks per batch
    const int tid = threadIdx.x;
    const int w   = tid >> 6;
    const int l   = tid & 63;

    // ---- stage batch once: 4 points per thread (3 float4 = 12 floats) ----
    {
        const float4* g4 = (const float4*)(pos + (size_t)b * 3072);
        const float4 A = g4[3 * tid], Bq = g4[3 * tid + 1], C = g4[3 * tid + 2];
        float* fx = (float*)sqx; float* fy = (float*)sqy; float* fz = (float*)sqz;
        const float px[4] = {A.x, A.w, Bq.z, C.y};
        const float py[4] = {A.y, Bq.x, Bq.w, C.z};
        const float pz[4] = {A.z, Bq.y, C.x, C.w};
#pragma unroll
        for (int u = 0; u < 4; ++u) {
            const int fo = fo_of(4 * tid + u);
            fx[fo] = px[u]; fy[fo] = py[u]; fz[fo] = pz[u];
        }
    }
    __syncthreads();

    const int goff = b << 10;
    float* const oSrc = out;
    float* const oTgt = out + EE;
    float* const oMsk = out + 2u * EE;
    float* const oDst = out + 3u * EE;
    int* const rows[2] = { slotrow[w][0], slotrow[w][1] };
    const int dump = 64 + l;              // per-lane dead entry

    // ---- 4 target-set iterations: wave handles targets i0, i0+1 ----
    for (int R = 0; R < 4; ++R) {
        const int i0 = __builtin_amdgcn_readfirstlane(
            ((blk & 7) << 5) | (R << 3) | (w << 1));   // even

        const float x0 = ((float*)sqx)[fo_of(i0)];
        const float y0 = ((float*)sqy)[fo_of(i0)];
        const float z0 = ((float*)sqz)[fo_of(i0)];
        const float x1 = ((float*)sqx)[fo_of(i0 + 1)];
        const float y1 = ((float*)sqy)[fo_of(i0 + 1)];
        const float z1 = ((float*)sqz)[fo_of(i0 + 1)];
        // (q + (-t)) == (q - t); (q-t)^2 == (t-q)^2 bitwise. Per-half op
        // order (dx^2+dy^2)+dz^2 matches the reference; asm pk ops cannot
        // be contracted. d2 < 36.0f is bit-identical to sqrt(d2) < 6.
        const v2f nx[2] = {{-x0, -x0}, {-x1, -x1}};
        const v2f ny[2] = {{-y0, -y0}, {-y1, -y1}};
        const v2f nz[2] = {{-z0, -z0}, {-z1, -z1}};

        const int gs = i0 >> 6;           // ii group holding both selves
        const int sl = i0 & 63;           // self lane of target 0 (T=1 -> +1)

        unsigned long long m0ii[2], m0io[2];
        int cii[2] = {0, 0};
        int cio[2] = {KK, KK};            // io biased +32: slots land [32,64)

        // ---- main scan: 8 pair-groups, both targets share the reads ----
#pragma unroll
        for (int p = 0; p < 8; ++p) {
            const v2f qx = sqx[(p << 6) + l];     // ds_read_b64 each
            const v2f qy = sqy[(p << 6) + l];
            const v2f qz = sqz[(p << 6) + l];
#pragma unroll
            for (int T = 0; T < 2; ++T) {
                const v2f dx = pk_add(qx, nx[T]), dy = pk_add(qy, ny[T]),
                          dz = pk_add(qz, nz[T]);
                const v2f d2 = pk_add(pk_add(pk_mul(dx, dx), pk_mul(dy, dy)),
                                      pk_mul(dz, dz));
#pragma unroll
                for (int h = 0; h < 2; ++h) {
                    const int g = 2 * p + h;          // 64-cand group
                    const int idxv = (g << 6) | l;    // candidate index
                    const float dh = h ? d2.y : d2.x;
                    bool pred = dh < 36.0f;
                    unsigned long long ms = __ballot(pred);
                    if (g == gs) {                    // wave-uniform, 1 of 16
                        ms &= ~(1ull << (sl + T));
                        pred = pred && (l != (sl + T));
                    }
                    if (g < 4) {                      // ii section
                        const int e = prefix_base(ms, cii[T]);
                        const bool wr = pred && (e < KK);
                        rows[T][wr ? e : dump] = idxv;
                        cii[T] += (int)__popcll(ms);
                        if (g == 0) m0ii[T] = ms;
                    } else {                          // io section (biased)
                        const int e = prefix_base(ms, cio[T]);
                        const bool wr = pred && (e < 2 * KK);
                        rows[T][wr ? e : dump] = idxv;
                        cio[T] += (int)__popcll(ms);
                        if (g == 4) m0io[T] = ms;
                    }
                }
            }
        }

        // ---- pads: single group each (sufficient whenever S0 < K) ----
#pragma unroll
        for (int T = 0; T < 2; ++T) {
            if (cii[T] < KK) {    // smallest ii invalids all in group 0
                const unsigned long long inv = ~m0ii[T];
                const int e = prefix_base(inv, cii[T]);
                const bool wr = ((inv >> l) & 1ull) && (e < KK);
                rows[T][wr ? e : dump] = l;           // cand = 0*64 + l
            }
            if (cio[T] < 2 * KK) {  // smallest io invalids all in group 4
                const unsigned long long inv = ~m0io[T];
                const int e = prefix_base(inv, cio[T]);
                const bool wr = ((inv >> l) & 1ull) && (e < 2 * KK);
                rows[T][wr ? e : dump] = 256 + l;     // cand = 4*64 + l
            }
        }

        // ---- epilogue: per target, 4 coalesced wave-wide stores ----
#pragma unroll
        for (int T = 0; T < 2; ++T) {
            const int idx = rows[T][l];   // same-wave RAW: lgkmcnt handles it
            const int fg = fo_of(idx);
            const float qx = ((float*)sqx)[fg], qy = ((float*)sqy)[fg],
                        qz = ((float*)sqz)[fg];
            const float xi = T ? x1 : x0, yi = T ? y1 : y0, zi = T ? z1 : z0;
            const float ddx = xi - qx, ddy = yi - qy, ddz = zi - qz;
            const float d2e = ddx * ddx + ddy * ddy + ddz * ddz;  // tol loose

            const bool isA = l < KK;      // lanes 0..31 = ii, 32..63 = io
            const int  Sa  = cii[T] < KK ? cii[T] : KK;
            const int  Sb  = (cio[T] < 2 * KK ? cio[T] : 2 * KK) - KK;
            const bool mv  = (l & 31) < (isA ? Sa : Sb);
            const float dist = mv ? __builtin_amdgcn_sqrtf(d2e) : 0.0f;

            const unsigned e0  = (unsigned)((b << 8) + i0 + T) << 5;
            const unsigned off = (isA ? 0u : 4u * EE - 32u) + e0 + (unsigned)l;

            oSrc[off] = (float)(goff + idx);      // src (io idx already >= 256)
            oTgt[off] = (float)(goff + i0 + T);   // tgt
            oMsk[off] = mv ? 1.0f : 0.0f;         // mask
            oDst[off] = dist;                     // dist
        }
    }
}

extern "C" void kernel_launch(void* const* d_in, const int* in_sizes, int n_in,
                              void* d_out, int out_size, void* d_ws, size_t ws_size,
                              hipStream_t stream) {
    const float* pos = (const float*)d_in[0];
    float* out = (float*)d_out;

    // 8 blocks/batch x 256 batches = 2048 blocks (8/CU, fully resident);
    // 256 threads = 4 waves x 2 targets x 4 iterations = 32 targets/block.
    mo3e_kernel<<<dim3(2048), dim3(256), 0, stream>>>(pos, out);
}